// Round 3
// baseline (331.521 us; speedup 1.0000x reference)
//
#include <hip/hip_runtime.h>

#define NPIX 12544   // 112*112
#define CDIM 512
#define QKVN 1536
#define HIDDEN 2048

typedef unsigned short u16;
typedef unsigned int u32;

typedef short bf16x8 __attribute__((ext_vector_type(8)));
typedef float f32x4 __attribute__((ext_vector_type(4)));

static __device__ __forceinline__ u16 f2bf(float f) {
  u32 u = __float_as_uint(f);
  return (u16)((u + 0x7fffu + ((u >> 16) & 1u)) >> 16);
}
static __device__ __forceinline__ u32 pack2(float a, float b) {
  return (u32)f2bf(a) | ((u32)f2bf(b) << 16);
}
// truncating bf16 pack of (lo,hi) via v_perm
static __device__ __forceinline__ u32 packtrunc2(float lo, float hi) {
  return __builtin_amdgcn_perm(__float_as_uint(hi), __float_as_uint(lo), 0x07060302u);
}
static __device__ __forceinline__ void async_ld16(const void* g, void* l) {
  __builtin_amdgcn_global_load_lds((__attribute__((address_space(1))) void*)g,
                                   (__attribute__((address_space(3))) void*)l, 16, 0, 0);
}

// ---------------- all weights fp32 -> bf16, one launch ----------------
__global__ __launch_bounds__(256) void convert_weights(
    const float* __restrict__ qw, const float* __restrict__ pw,
    const float* __restrict__ w1, const float* __restrict__ w2,
    u16* __restrict__ Wq, u16* __restrict__ Wp, u16* __restrict__ W1o, u16* __restrict__ W2o) {
  const int b = blockIdx.x;
  const float* src; u16* dst; long off;
  if (b < 768)       { src = qw; dst = Wq;  off = (long)b * 1024; }
  else if (b < 1024) { src = pw; dst = Wp;  off = (long)(b - 768) * 1024; }
  else if (b < 2048) { src = w1; dst = W1o; off = (long)(b - 1024) * 1024; }
  else               { src = w2; dst = W2o; off = (long)(b - 2048) * 1024; }
  const long i = off / 4 + threadIdx.x;
  const float4 v = ((const float4*)src)[i];
  ushort4 u;
  u.x = f2bf(v.x); u.y = f2bf(v.y); u.z = f2bf(v.z); u.w = f2bf(v.w);
  ((ushort4*)dst)[i] = u;
}

// ---------------- LN1 stats (partials over 32-channel chunks) ----------------
__global__ __launch_bounds__(256) void ln1_partial(const float* __restrict__ x,
                                                   float* __restrict__ psum, float* __restrict__ pssq) {
  const int p = blockIdx.x * 256 + threadIdx.x;
  const int c0 = blockIdx.y * 32;
  float s = 0.f, ss = 0.f;
#pragma unroll
  for (int c = 0; c < 32; c++) {
    const float v = x[(long)(c0 + c) * NPIX + p];
    s += v; ss += v * v;
  }
  psum[blockIdx.y * NPIX + p] = s;
  pssq[blockIdx.y * NPIX + p] = ss;
}

__global__ __launch_bounds__(256) void ln1_stats(const float* __restrict__ psum, const float* __restrict__ pssq,
                                                 float* __restrict__ mean, float* __restrict__ rstd) {
  const int p = blockIdx.x * 256 + threadIdx.x;
  float s = 0.f, ss = 0.f;
#pragma unroll
  for (int ch = 0; ch < 16; ch++) { s += psum[ch * NPIX + p]; ss += pssq[ch * NPIX + p]; }
  const float m = s * (1.f / 512.f);
  const float v = ss * (1.f / 512.f) - m * m;
  mean[p] = m;
  rstd[p] = rsqrtf(v + 1e-5f);
}

// ------- LN1 apply + cyclic shift + window partition -> xw [token, C] bf16 -------
__global__ __launch_bounds__(256) void ln1_shift_part(const float* __restrict__ x,
    const float* __restrict__ mean, const float* __restrict__ rstd,
    const float* __restrict__ gw, const float* __restrict__ gb, u16* __restrict__ xw) {
  __shared__ float tile[32][65];
  const int p0 = blockIdx.x * 64;
  const int c0 = blockIdx.y * 32;
  const int t = threadIdx.x;
  {
    const int pl = t & 63;
    const int cl0 = t >> 6;
#pragma unroll
    for (int r = 0; r < 8; r++) {
      const int cl = r * 4 + cl0;
      tile[cl][pl] = x[(long)(c0 + cl) * NPIX + p0 + pl];
    }
  }
  __syncthreads();
  const int cl = t & 31;
  const int g = t >> 5;
  const float wc = gw[c0 + cl];
  const float bc = gb[c0 + cl];
#pragma unroll
  for (int pass = 0; pass < 8; pass++) {
    const int pl = pass * 8 + g;
    const int p = p0 + pl;
    const int h = p / 112;
    const int w = p - h * 112;
    int hs = h + 109; if (hs >= 112) hs -= 112;
    int ws2 = w + 109; if (ws2 >= 112) ws2 -= 112;
    const int hq = hs / 7, wq = ws2 / 7;
    const int tok = (hq * 16 + wq) * 49 + (hs - hq * 7) * 7 + (ws2 - wq * 7);
    const float val = (tile[cl][pl] - mean[p]) * rstd[p] * wc + bc;
    xw[(long)tok * 512 + c0 + cl] = f2bf(val);
  }
}

// ---------------- GEMM: C[M,N] = A[M,K] @ B[N,K]^T + bias ----------------
// Transposed-C MFMA (operand swap): lane = M-row, regs = 4 consecutive N-cols.
// LDS chunk-XOR swizzle kills 8-way bank conflicts on fragment reads.
template<bool OUT_BF16, bool DO_GELU, bool REMAP>
__global__ __launch_bounds__(256, 3) void gemm_bt(
    const u16* __restrict__ A, const u16* __restrict__ B,
    const float* __restrict__ bias, void* __restrict__ out,
    const int N, const int K) {
  __shared__ __align__(16) u16 Asm[128 * 32];
  __shared__ __align__(16) u16 Bsm[128 * 32];
  const int M0 = blockIdx.x << 7;
  const int N0 = blockIdx.y << 7;
  const int t = threadIdx.x;
  const int wave = t >> 6;
  const int lane = t & 63;
  const int l15 = lane & 15;
  const int quad = lane >> 4;
  const int wm = wave & 1;
  const int wn = wave >> 1;
  const int swz = (l15 >> 1) & 3;           // fragment-read chunk swizzle

  f32x4 acc[4][4] = {};

  for (int k0 = 0; k0 < K; k0 += 32) {
#pragma unroll
    for (int i = 0; i < 2; i++) {
      const int flatbase = i * 256 + wave * 64;   // wave-uniform LDS base
      const int FL = flatbase + lane;
      const int row = FL >> 2;
      const int chunk = (FL & 3) ^ ((row >> 1) & 3);   // staged-swizzle source chunk
      async_ld16(A + (long)(M0 + row) * K + k0 + chunk * 8, &Asm[flatbase * 8]);
      async_ld16(B + (long)(N0 + row) * K + k0 + chunk * 8, &Bsm[flatbase * 8]);
    }
    __syncthreads();
    bf16x8 af[4], bfr[4];
#pragma unroll
    for (int im = 0; im < 4; im++)
      af[im] = *(const bf16x8*)&Asm[(wm * 64 + im * 16 + l15) * 32 + (quad ^ swz) * 8];
#pragma unroll
    for (int in = 0; in < 4; in++)
      bfr[in] = *(const bf16x8*)&Bsm[(wn * 64 + in * 16 + l15) * 32 + (quad ^ swz) * 8];
#pragma unroll
    for (int im = 0; im < 4; im++)
#pragma unroll
      for (int in = 0; in < 4; in++)
        acc[im][in] = __builtin_amdgcn_mfma_f32_16x16x32_bf16(bfr[in], af[im], acc[im][in], 0, 0, 0);
    __syncthreads();
  }

#pragma unroll
  for (int im = 0; im < 4; im++) {
    const int row = M0 + wm * 64 + im * 16 + l15;
    long orow = row;
    if (REMAP) {  // window-token -> pixel (un-partition + reverse shift)
      const int win = row / 49;
      const int nn = row - win * 49;
      const int nq = nn / 7;
      const int hs = (win >> 4) * 7 + nq;
      const int wsx = (win & 15) * 7 + (nn - nq * 7);
      int h = hs + 3; if (h >= 112) h -= 112;
      int w = wsx + 3; if (w >= 112) w -= 112;
      orow = h * 112 + w;
    }
#pragma unroll
    for (int in = 0; in < 4; in++) {
      const int col0 = N0 + wn * 64 + in * 16 + quad * 4;
      const float4 bv = *(const float4*)(bias + col0);
      float v[4];
#pragma unroll
      for (int r = 0; r < 4; r++) {
        float vv = acc[im][in][r] + ((const float*)&bv)[r];
        if (DO_GELU) {
          const float z2 = 1.5957691216f * (vv + 0.044715f * vv * vv * vv);
          vv = vv / (1.0f + __expf(-z2));
        }
        v[r] = vv;
      }
      if (OUT_BF16) {
        uint2 u;
        u.x = pack2(v[0], v[1]);
        u.y = pack2(v[2], v[3]);
        *(uint2*)((u16*)out + orow * (long)N + col0) = u;
      } else {
        float4 f; f.x = v[0]; f.y = v[1]; f.z = v[2]; f.w = v[3];
        *(float4*)((float*)out + orow * (long)N + col0) = f;
      }
    }
  }
}

// -------- biasT[cls][head][j][i] = rpb bias + shift-mask + pad-mask (Swin) --------
__global__ __launch_bounds__(256) void build_biasT(const float* __restrict__ rpb, float* __restrict__ biasT) {
  const int cls = blockIdx.x >> 4;
  const int head = blockIdx.x & 15;
  for (int e = threadIdx.x; e < 4096; e += 256) {
    const int j = e >> 6;   // key
    const int i = e & 63;   // query
    float v;
    if (j >= 49) v = -1e9f;
    else if (i >= 49) v = 0.f;
    else {
      const int ri = i / 7, ci = i - (i / 7) * 7;
      const int rj = j / 7, cj = j - (j / 7) * 7;
      v = rpb[((ri - rj + 6) * 13 + (ci - cj + 6)) * 16 + head];
      const int lhi = (cls & 2) ? (ri < 4 ? 1 : 2) : 0;
      const int lwi = (cls & 1) ? (ci < 4 ? 1 : 2) : 0;
      const int lhj = (cls & 2) ? (rj < 4 ? 1 : 2) : 0;
      const int lwj = (cls & 1) ? (cj < 4 ? 1 : 2) : 0;
      if (lhi * 3 + lwi != lhj * 3 + lwj) v = -1e9f;
    }
    biasT[(long)blockIdx.x * 4096 + e] = v;
  }
}

// ---------------- MFMA attention: one wave per (window, head) ----------------
__global__ __launch_bounds__(256, 3) void attn_mfma(
    const u16* __restrict__ qkv, const float* __restrict__ biasT, u16* __restrict__ out) {
  __shared__ __align__(16) u16 slds[24576];   // 4 waves x 12KB
  const int t = threadIdx.x;
  const int wave = t >> 6;
  const int lane = t & 63;
  const int l15 = lane & 15;
  const int quad = lane >> 4;
  const int win = blockIdx.x >> 2;
  const int head = (blockIdx.x & 3) * 4 + wave;
  const int cls = (((win >> 4) == 15) ? 2 : 0) | (((win & 15) == 15) ? 1 : 0);

  u16* Qb  = slds + wave * 6144;
  u16* Kb  = Qb + 2048;
  u16* Vtb = Qb + 4096;
  u16* Pb  = Qb;          // P [64][64] overlays Q+K after S is consumed

  // ---- stage Q,K via global_load_lds (chunk-swizzled); V into regs ----
  const int rrow = lane >> 2;
  const int chunk = (lane & 3) ^ ((lane >> 3) & 3);   // swizzled source chunk
  uint4 vv[4];
#pragma unroll
  for (int it = 0; it < 4; it++) {
    const int row = it * 16 + rrow;
    const int jc = row < 49 ? row : 48;
    const long gbase = (long)(win * 49 + jc) * 1536 + head * 32 + chunk * 8;
    async_ld16(qkv + gbase,       Qb + it * 512 + lane * 8);
    async_ld16(qkv + gbase + 512, Kb + it * 512 + lane * 8);
    vv[it] = *(const uint4*)(qkv + gbase + 1024);
  }
  __syncthreads();

  // ---- V^T build: Vt[d][j], j swizzled by ((d>>2)&3)<<4 ----
#pragma unroll
  for (int it = 0; it < 4; it++) {
    const int row = it * 16 + rrow;
    const u32* w = (const u32*)&vv[it];
#pragma unroll
    for (int tt = 0; tt < 8; tt++) {
      const int d = chunk * 8 + tt;
      const u16 val = (tt & 1) ? (u16)(w[tt >> 1] >> 16) : (u16)(w[tt >> 1] & 0xffffu);
      Vtb[d * 64 + (row ^ (((d >> 2) & 3) << 4))] = val;
    }
  }

  // ---- S^T = K * Q^T ----
  const int fswz = (l15 >> 1) & 3;
  bf16x8 kfrag[4], qfrag[4];
#pragma unroll
  for (int jm = 0; jm < 4; jm++)
    kfrag[jm] = *(const bf16x8*)(Kb + (jm * 16 + l15) * 32 + (quad ^ fswz) * 8);
#pragma unroll
  for (int in = 0; in < 4; in++)
    qfrag[in] = *(const bf16x8*)(Qb + (in * 16 + l15) * 32 + (quad ^ fswz) * 8);
  f32x4 sacc[4][4] = {};
#pragma unroll
  for (int jm = 0; jm < 4; jm++)
#pragma unroll
    for (int in = 0; in < 4; in++)
      sacc[jm][in] = __builtin_amdgcn_mfma_f32_16x16x32_bf16(kfrag[jm], qfrag[in], sacc[jm][in], 0, 0, 0);

  // ---- epilogue: scale + bias/mask gather, softmax over j ----
  const float* bT = biasT + (long)(cls * 16 + head) * 4096;
  const float sc = 0.17677669529663687f;
#pragma unroll
  for (int jm = 0; jm < 4; jm++) {
    const float* bp = bT + (jm * 16 + quad * 4) * 64 + l15;
#pragma unroll
    for (int in = 0; in < 4; in++)
#pragma unroll
      for (int r = 0; r < 4; r++)
        sacc[jm][in][r] = sacc[jm][in][r] * sc + bp[r * 64 + in * 16];
  }
  float linv[4];
#pragma unroll
  for (int in = 0; in < 4; in++) {
    float m = -1e30f;
#pragma unroll
    for (int jm = 0; jm < 4; jm++)
#pragma unroll
      for (int r = 0; r < 4; r++) m = fmaxf(m, sacc[jm][in][r]);
    m = fmaxf(m, __shfl_xor(m, 16));
    m = fmaxf(m, __shfl_xor(m, 32));
    float s = 0.f;
#pragma unroll
    for (int jm = 0; jm < 4; jm++)
#pragma unroll
      for (int r = 0; r < 4; r++) {
        const float e = __expf(sacc[jm][in][r] - m);
        sacc[jm][in][r] = e; s += e;
      }
    s += __shfl_xor(s, 16);
    s += __shfl_xor(s, 32);
    linv[in] = __builtin_amdgcn_rcpf(s);
  }

  // ---- P -> LDS bf16 (trunc), XOR-swizzled ----
#pragma unroll
  for (int in = 0; in < 4; in++) {
    const int i = in * 16 + l15;
    const int rot = (l15 & 3) << 4;
#pragma unroll
    for (int jm = 0; jm < 4; jm++) {
      const u32 lo = packtrunc2(sacc[jm][in][0], sacc[jm][in][1]);
      const u32 hi = packtrunc2(sacc[jm][in][2], sacc[jm][in][3]);
      uint2 u; u.x = lo; u.y = hi;
      *(uint2*)(Pb + i * 64 + ((jm * 16 + quad * 4) ^ rot)) = u;
    }
  }

  // ---- O^T = V^T * P ----
  f32x4 oacc[2][4] = {};
#pragma unroll
  for (int ks = 0; ks < 2; ks++) {
    bf16x8 vtf[2], pf[4];
#pragma unroll
    for (int dm = 0; dm < 2; dm++)
      vtf[dm] = *(const bf16x8*)(Vtb + (dm * 16 + l15) * 64 + ((ks * 32 + quad * 8) ^ ((l15 >> 2) << 4)));
#pragma unroll
    for (int in = 0; in < 4; in++)
      pf[in] = *(const bf16x8*)(Pb + (in * 16 + l15) * 64 + ((ks * 32 + quad * 8) ^ ((l15 & 3) << 4)));
#pragma unroll
    for (int dm = 0; dm < 2; dm++)
#pragma unroll
      for (int in = 0; in < 4; in++)
        oacc[dm][in] = __builtin_amdgcn_mfma_f32_16x16x32_bf16(vtf[dm], pf[in], oacc[dm][in], 0, 0, 0);
  }

  // ---- store O (4 consecutive channels per lane, 8B packed) ----
#pragma unroll
  for (int in = 0; in < 4; in++) {
    const int i = in * 16 + l15;
    if (i < 49) {
      const float inv = linv[in];
      const long base = (long)(win * 49 + i) * 512 + head * 32 + quad * 4;
#pragma unroll
      for (int dm = 0; dm < 2; dm++) {
        const float v0 = oacc[dm][in][0] * inv, v1 = oacc[dm][in][1] * inv;
        const float v2 = oacc[dm][in][2] * inv, v3 = oacc[dm][in][3] * inv;
        uint2 u; u.x = packtrunc2(v0, v1); u.y = packtrunc2(v2, v3);
        *(uint2*)(out + base + dm * 16) = u;
      }
    }
  }
}

// ---------------- x1 = x(CHW) + proj_out(pixel,C) ----------------
__global__ __launch_bounds__(256) void resid_kernel(const float* __restrict__ x,
    const float* __restrict__ proj, float* __restrict__ x1) {
  __shared__ float tile[32][65];
  const int p0 = blockIdx.x * 64;
  const int c0 = blockIdx.y * 32;
  const int t = threadIdx.x;
  {
    const int pl = t & 63;
    const int cl0 = t >> 6;
#pragma unroll
    for (int r = 0; r < 8; r++) {
      const int cl = r * 4 + cl0;
      tile[cl][pl] = x[(long)(c0 + cl) * NPIX + p0 + pl];
    }
  }
  __syncthreads();
  const int cl = t & 31;
  const int g = t >> 5;
#pragma unroll
  for (int pass = 0; pass < 8; pass++) {
    const int pl = pass * 8 + g;
    const long idx = (long)(p0 + pl) * 512 + c0 + cl;
    x1[idx] = tile[cl][pl] + proj[idx];
  }
}

// ---------------- LN2: wave per pixel row ----------------
__global__ __launch_bounds__(256) void ln2_apply(const float* __restrict__ x1,
    const float* __restrict__ gw, const float* __restrict__ gb, u16* __restrict__ x2) {
  const int wave = threadIdx.x >> 6;
  const int lane = threadIdx.x & 63;
  const int p = blockIdx.x * 4 + wave;
  const float4* row = (const float4*)(x1 + (long)p * 512);
  const float4 a = row[lane * 2];
  const float4 b = row[lane * 2 + 1];
  float s = a.x + a.y + a.z + a.w + b.x + b.y + b.z + b.w;
  float ss = a.x * a.x + a.y * a.y + a.z * a.z + a.w * a.w
           + b.x * b.x + b.y * b.y + b.z * b.z + b.w * b.w;
#pragma unroll
  for (int o = 32; o > 0; o >>= 1) { s += __shfl_xor(s, o); ss += __shfl_xor(ss, o); }
  const float m = s * (1.f / 512.f);
  const float var = ss * (1.f / 512.f) - m * m;
  const float rs = rsqrtf(var + 1e-5f);
  const float4 w0 = ((const float4*)gw)[lane * 2];
  const float4 w1 = ((const float4*)gw)[lane * 2 + 1];
  const float4 b0 = ((const float4*)gb)[lane * 2];
  const float4 b1 = ((const float4*)gb)[lane * 2 + 1];
  uint4 u;
  u.x = pack2((a.x - m) * rs * w0.x + b0.x, (a.y - m) * rs * w0.y + b0.y);
  u.y = pack2((a.z - m) * rs * w0.z + b0.z, (a.w - m) * rs * w0.w + b0.w);
  u.z = pack2((b.x - m) * rs * w1.x + b1.x, (b.y - m) * rs * w1.y + b1.y);
  u.w = pack2((b.z - m) * rs * w1.z + b1.z, (b.w - m) * rs * w1.w + b1.w);
  ((uint4*)(x2 + (long)p * 512))[lane] = u;
}

// ---------------- y[C,H,W] = x1[p,C] + m[p,C] ----------------
__global__ __launch_bounds__(256) void final_kernel(const float* __restrict__ x1,
    const float* __restrict__ mm, float* __restrict__ y) {
  __shared__ float tile[32][65];
  const int p0 = blockIdx.x * 64;
  const int c0 = blockIdx.y * 32;
  const int t = threadIdx.x;
  {
    const int cl = t & 31;
    const int g = t >> 5;
#pragma unroll
    for (int pass = 0; pass < 8; pass++) {
      const int pl = pass * 8 + g;
      const long idx = (long)(p0 + pl) * 512 + c0 + cl;
      tile[cl][pl] = x1[idx] + mm[idx];
    }
  }
  __syncthreads();
  const int pl = t & 63;
  const int cl0 = t >> 6;
#pragma unroll
  for (int r = 0; r < 8; r++) {
    const int cl = r * 4 + cl0;
    y[(long)(c0 + cl) * NPIX + p0 + pl] = tile[cl][pl];
  }
}

extern "C" void kernel_launch(void* const* d_in, const int* in_sizes, int n_in,
                              void* d_out, int out_size, void* d_ws, size_t ws_size,
                              hipStream_t stream) {
  (void)in_sizes; (void)n_in; (void)out_size; (void)ws_size;
  const float* x      = (const float*)d_in[0];
  const float* n1w    = (const float*)d_in[1];
  const float* n1b    = (const float*)d_in[2];
  const float* qkv_w  = (const float*)d_in[3];
  const float* qkv_b  = (const float*)d_in[4];
  const float* proj_w = (const float*)d_in[5];
  const float* proj_b = (const float*)d_in[6];
  const float* rpb    = (const float*)d_in[7];
  const float* n2w    = (const float*)d_in[8];
  const float* n2b    = (const float*)d_in[9];
  const float* fc1_w  = (const float*)d_in[10];
  const float* fc1_b  = (const float*)d_in[11];
  const float* fc2_w  = (const float*)d_in[12];
  const float* fc2_b  = (const float*)d_in[13];
  float* y = (float*)d_out;

  char* base = (char*)d_ws;
  size_t off = 0;
  auto alloc = [&](size_t b) { char* p = base + off; off += (b + 255) & ~(size_t)255; return p; };
  float* mean1 = (float*)alloc((size_t)NPIX * 4);
  float* rstd1 = (float*)alloc((size_t)NPIX * 4);
  float* psum  = (float*)alloc((size_t)16 * NPIX * 4);
  float* pssq  = (float*)alloc((size_t)16 * NPIX * 4);
  u16* Wq = (u16*)alloc((size_t)QKVN * CDIM * 2);
  u16* Wp = (u16*)alloc((size_t)CDIM * CDIM * 2);
  u16* W1 = (u16*)alloc((size_t)HIDDEN * CDIM * 2);
  u16* W2 = (u16*)alloc((size_t)CDIM * HIDDEN * 2);
  float* biasT = (float*)alloc((size_t)4 * 16 * 4096 * 4);
  u16* bufA = (u16*)alloc((size_t)NPIX * CDIM * 2);
  char* bufB = alloc((size_t)NPIX * QKVN * 2);
  float* x1 = (float*)alloc((size_t)NPIX * CDIM * 4);
  u16* hbuf = (u16*)alloc((size_t)NPIX * HIDDEN * 2);

  u16* xw      = bufA;
  u16* qkvbuf  = (u16*)bufB;
  u16* attnout = bufA;
  float* projout = (float*)bufB;
  u16* x2 = bufA;
  float* mbuf = (float*)bufB;

  convert_weights<<<3072, 256, 0, stream>>>(qkv_w, proj_w, fc1_w, fc2_w, Wq, Wp, W1, W2);
  build_biasT<<<64, 256, 0, stream>>>(rpb, biasT);

  ln1_partial<<<dim3(49, 16), 256, 0, stream>>>(x, psum, pssq);
  ln1_stats<<<49, 256, 0, stream>>>(psum, pssq, mean1, rstd1);
  ln1_shift_part<<<dim3(196, 16), 256, 0, stream>>>(x, mean1, rstd1, n1w, n1b, xw);

  gemm_bt<true, false, false><<<dim3(98, QKVN / 128), 256, 0, stream>>>(xw, Wq, qkv_b, qkvbuf, QKVN, CDIM);
  attn_mfma<<<1024, 256, 0, stream>>>(qkvbuf, biasT, attnout);
  gemm_bt<false, false, true><<<dim3(98, CDIM / 128), 256, 0, stream>>>(attnout, Wp, proj_b, projout, CDIM, CDIM);

  resid_kernel<<<dim3(196, 16), 256, 0, stream>>>(x, projout, x1);
  ln2_apply<<<NPIX / 4, 256, 0, stream>>>(x1, n2w, n2b, x2);

  gemm_bt<true, true, false><<<dim3(98, HIDDEN / 128), 256, 0, stream>>>(x2, W1, fc1_b, hbuf, HIDDEN, CDIM);
  gemm_bt<false, false, false><<<dim3(98, CDIM / 128), 256, 0, stream>>>(hbuf, W2, fc2_b, mbuf, CDIM, HIDDEN);

  final_kernel<<<dim3(196, 16), 256, 0, stream>>>(x1, mbuf, y);
}

// Round 4
// 306.638 us; speedup vs baseline: 1.0811x; 1.0811x over previous
//
#include <hip/hip_runtime.h>

#define NPIX 12544   // 112*112
#define CDIM 512
#define QKVN 1536
#define HIDDEN 2048

typedef unsigned short u16;
typedef unsigned int u32;

typedef short bf16x8 __attribute__((ext_vector_type(8)));
typedef float f32x4 __attribute__((ext_vector_type(4)));

static __device__ __forceinline__ u16 f2bf(float f) {
  u32 u = __float_as_uint(f);
  return (u16)((u + 0x7fffu + ((u >> 16) & 1u)) >> 16);
}
static __device__ __forceinline__ u32 pack2(float a, float b) {
  return (u32)f2bf(a) | ((u32)f2bf(b) << 16);
}
// truncating bf16 pack of (lo,hi) via v_perm
static __device__ __forceinline__ u32 packtrunc2(float lo, float hi) {
  return __builtin_amdgcn_perm(__float_as_uint(hi), __float_as_uint(lo), 0x07060302u);
}
static __device__ __forceinline__ void async_ld16(const void* g, void* l) {
  __builtin_amdgcn_global_load_lds((__attribute__((address_space(1))) void*)g,
                                   (__attribute__((address_space(3))) void*)l, 16, 0, 0);
}

// ---------------- all weights fp32 -> bf16, one launch ----------------
__global__ __launch_bounds__(256) void convert_weights(
    const float* __restrict__ qw, const float* __restrict__ pw,
    const float* __restrict__ w1, const float* __restrict__ w2,
    u16* __restrict__ Wq, u16* __restrict__ Wp, u16* __restrict__ W1o, u16* __restrict__ W2o) {
  const int b = blockIdx.x;
  const float* src; u16* dst; long off;
  if (b < 768)       { src = qw; dst = Wq;  off = (long)b * 1024; }
  else if (b < 1024) { src = pw; dst = Wp;  off = (long)(b - 768) * 1024; }
  else if (b < 2048) { src = w1; dst = W1o; off = (long)(b - 1024) * 1024; }
  else               { src = w2; dst = W2o; off = (long)(b - 2048) * 1024; }
  const long i = off / 4 + threadIdx.x;
  const float4 v = ((const float4*)src)[i];
  ushort4 u;
  u.x = f2bf(v.x); u.y = f2bf(v.y); u.z = f2bf(v.z); u.w = f2bf(v.w);
  ((ushort4*)dst)[i] = u;
}

// ---------------- LN1 stats (partials over 32-channel chunks) ----------------
__global__ __launch_bounds__(256) void ln1_partial(const float* __restrict__ x,
                                                   float* __restrict__ psum, float* __restrict__ pssq) {
  const int p = blockIdx.x * 256 + threadIdx.x;
  const int c0 = blockIdx.y * 32;
  float s = 0.f, ss = 0.f;
#pragma unroll
  for (int c = 0; c < 32; c++) {
    const float v = x[(long)(c0 + c) * NPIX + p];
    s += v; ss += v * v;
  }
  psum[blockIdx.y * NPIX + p] = s;
  pssq[blockIdx.y * NPIX + p] = ss;
}

__global__ __launch_bounds__(256) void ln1_stats(const float* __restrict__ psum, const float* __restrict__ pssq,
                                                 float* __restrict__ mean, float* __restrict__ rstd) {
  const int p = blockIdx.x * 256 + threadIdx.x;
  float s = 0.f, ss = 0.f;
#pragma unroll
  for (int ch = 0; ch < 16; ch++) { s += psum[ch * NPIX + p]; ss += pssq[ch * NPIX + p]; }
  const float m = s * (1.f / 512.f);
  const float v = ss * (1.f / 512.f) - m * m;
  mean[p] = m;
  rstd[p] = rsqrtf(v + 1e-5f);
}

// ------- LN1 apply + cyclic shift + window partition -> xw [token, C] bf16 -------
__global__ __launch_bounds__(256) void ln1_shift_part(const float* __restrict__ x,
    const float* __restrict__ mean, const float* __restrict__ rstd,
    const float* __restrict__ gw, const float* __restrict__ gb, u16* __restrict__ xw) {
  __shared__ float tile[32][65];
  const int p0 = blockIdx.x * 64;
  const int c0 = blockIdx.y * 32;
  const int t = threadIdx.x;
  {
    const int pl = t & 63;
    const int cl0 = t >> 6;
#pragma unroll
    for (int r = 0; r < 8; r++) {
      const int cl = r * 4 + cl0;
      tile[cl][pl] = x[(long)(c0 + cl) * NPIX + p0 + pl];
    }
  }
  __syncthreads();
  const int cl = t & 31;
  const int g = t >> 5;
  const float wc = gw[c0 + cl];
  const float bc = gb[c0 + cl];
#pragma unroll
  for (int pass = 0; pass < 8; pass++) {
    const int pl = pass * 8 + g;
    const int p = p0 + pl;
    const int h = p / 112;
    const int w = p - h * 112;
    int hs = h + 109; if (hs >= 112) hs -= 112;
    int ws2 = w + 109; if (ws2 >= 112) ws2 -= 112;
    const int hq = hs / 7, wq = ws2 / 7;
    const int tok = (hq * 16 + wq) * 49 + (hs - hq * 7) * 7 + (ws2 - wq * 7);
    const float val = (tile[cl][pl] - mean[p]) * rstd[p] * wc + bc;
    xw[(long)tok * 512 + c0 + cl] = f2bf(val);
  }
}

// ---------------- GEMM: C[M,N] = A[M,K] @ B[N,K]^T + bias ----------------
// BK=64 K-steps (32 MFMA per barrier pair), transposed-C MFMA, 8-chunk XOR swizzle.
// FUSE_Y: epilogue computes y[c][p] = acc + bias[c] + x1[p][c] (fc2 + residual + transpose).
template<bool OUT_BF16, bool DO_GELU, bool REMAP, bool FUSE_Y>
__global__ __launch_bounds__(256, 3) void gemm_bt(
    const u16* __restrict__ A, const u16* __restrict__ B,
    const float* __restrict__ bias, void* __restrict__ out,
    const float* __restrict__ x1, const int N, const int K) {
  __shared__ __align__(16) u16 Asm[128 * 64];
  __shared__ __align__(16) u16 Bsm[128 * 64];
  const int M0 = blockIdx.x << 7;
  const int N0 = blockIdx.y << 7;
  const int t = threadIdx.x;
  const int wave = t >> 6;
  const int lane = t & 63;
  const int l15 = lane & 15;
  const int quad = lane >> 4;
  const int wm = wave & 1;
  const int wn = wave >> 1;
  const int swz8 = l15 & 7;                 // fragment-read chunk swizzle

  f32x4 acc[4][4] = {};

  for (int k0 = 0; k0 < K; k0 += 64) {
#pragma unroll
    for (int i = 0; i < 4; i++) {
      const int flatbase = i * 256 + wave * 64;      // 16B-chunk index, wave-uniform base
      const int FL = flatbase + lane;
      const int row = FL >> 3;
      const int c = (FL & 7) ^ (row & 7);            // staged-swizzle source chunk
      async_ld16(A + (long)(M0 + row) * K + k0 + c * 8, Asm + flatbase * 8);
      async_ld16(B + (long)(N0 + row) * K + k0 + c * 8, Bsm + flatbase * 8);
    }
    __syncthreads();
#pragma unroll
    for (int ks = 0; ks < 2; ks++) {
      bf16x8 af[4], bfr[4];
#pragma unroll
      for (int im = 0; im < 4; im++)
        af[im] = *(const bf16x8*)&Asm[(wm * 64 + im * 16 + l15) * 64 + ((ks * 4 + quad) ^ swz8) * 8];
#pragma unroll
      for (int in = 0; in < 4; in++)
        bfr[in] = *(const bf16x8*)&Bsm[(wn * 64 + in * 16 + l15) * 64 + ((ks * 4 + quad) ^ swz8) * 8];
#pragma unroll
      for (int im = 0; im < 4; im++)
#pragma unroll
        for (int in = 0; in < 4; in++)
          acc[im][in] = __builtin_amdgcn_mfma_f32_16x16x32_bf16(bfr[in], af[im], acc[im][in], 0, 0, 0);
    }
    __syncthreads();
  }

#pragma unroll
  for (int im = 0; im < 4; im++) {
    const int row = M0 + wm * 64 + im * 16 + l15;
    long orow = row;
    if (REMAP) {  // window-token -> pixel (un-partition + reverse shift)
      const int win = row / 49;
      const int nn = row - win * 49;
      const int nq = nn / 7;
      const int hs = (win >> 4) * 7 + nq;
      const int wsx = (win & 15) * 7 + (nn - nq * 7);
      int h = hs + 3; if (h >= 112) h -= 112;
      int w = wsx + 3; if (w >= 112) w -= 112;
      orow = h * 112 + w;
    }
#pragma unroll
    for (int in = 0; in < 4; in++) {
      const int col0 = N0 + wn * 64 + in * 16 + quad * 4;
      const float4 bv = *(const float4*)(bias + col0);
      float v[4];
      if (FUSE_Y) {
        const float4 xv = *(const float4*)(x1 + (long)row * CDIM + col0);
#pragma unroll
        for (int r = 0; r < 4; r++)
          v[r] = acc[im][in][r] + ((const float*)&bv)[r] + ((const float*)&xv)[r];
#pragma unroll
        for (int r = 0; r < 4; r++)
          ((float*)out)[(long)(col0 + r) * NPIX + row] = v[r];   // y[C, HW]
      } else {
#pragma unroll
        for (int r = 0; r < 4; r++) {
          float vv = acc[im][in][r] + ((const float*)&bv)[r];
          if (DO_GELU) {
            const float z2 = 1.5957691216f * (vv + 0.044715f * vv * vv * vv);
            vv = vv / (1.0f + __expf(-z2));
          }
          v[r] = vv;
        }
        if (OUT_BF16) {
          uint2 u;
          u.x = pack2(v[0], v[1]);
          u.y = pack2(v[2], v[3]);
          *(uint2*)((u16*)out + orow * (long)N + col0) = u;
        } else {
          float4 f; f.x = v[0]; f.y = v[1]; f.z = v[2]; f.w = v[3];
          *(float4*)((float*)out + orow * (long)N + col0) = f;
        }
      }
    }
  }
}

// -------- biasT[cls][head][j][i] = rpb bias + shift-mask + pad-mask (Swin) --------
__global__ __launch_bounds__(256) void build_biasT(const float* __restrict__ rpb, float* __restrict__ biasT) {
  const int cls = blockIdx.x >> 4;
  const int head = blockIdx.x & 15;
  for (int e = threadIdx.x; e < 4096; e += 256) {
    const int j = e >> 6;   // key
    const int i = e & 63;   // query
    float v;
    if (j >= 49) v = -1e9f;
    else if (i >= 49) v = 0.f;
    else {
      const int ri = i / 7, ci = i - (i / 7) * 7;
      const int rj = j / 7, cj = j - (j / 7) * 7;
      v = rpb[((ri - rj + 6) * 13 + (ci - cj + 6)) * 16 + head];
      const int lhi = (cls & 2) ? (ri < 4 ? 1 : 2) : 0;
      const int lwi = (cls & 1) ? (ci < 4 ? 1 : 2) : 0;
      const int lhj = (cls & 2) ? (rj < 4 ? 1 : 2) : 0;
      const int lwj = (cls & 1) ? (cj < 4 ? 1 : 2) : 0;
      if (lhi * 3 + lwi != lhj * 3 + lwj) v = -1e9f;
    }
    biasT[(long)blockIdx.x * 4096 + e] = v;
  }
}

// ---------------- MFMA attention: one wave per (window, head) ----------------
__global__ __launch_bounds__(256, 3) void attn_mfma(
    const u16* __restrict__ qkv, const float* __restrict__ biasT, u16* __restrict__ out) {
  __shared__ __align__(16) u16 slds[24576];   // 4 waves x 12KB
  const int t = threadIdx.x;
  const int wave = t >> 6;
  const int lane = t & 63;
  const int l15 = lane & 15;
  const int quad = lane >> 4;
  const int win = blockIdx.x >> 2;
  const int head = (blockIdx.x & 3) * 4 + wave;
  const int cls = (((win >> 4) == 15) ? 2 : 0) | (((win & 15) == 15) ? 1 : 0);

  u16* Qb  = slds + wave * 6144;
  u16* Kb  = Qb + 2048;
  u16* Vtb = Qb + 4096;
  u16* Pb  = Qb;          // P [64][64] overlays Q+K after S is consumed

  // ---- stage Q,K via global_load_lds (chunk-swizzled); V into regs ----
  const int rrow = lane >> 2;
  const int chunk = (lane & 3) ^ ((lane >> 3) & 3);   // swizzled source chunk
  uint4 vv[4];
#pragma unroll
  for (int it = 0; it < 4; it++) {
    const int row = it * 16 + rrow;
    const int jc = row < 49 ? row : 48;
    const long gbase = (long)(win * 49 + jc) * 1536 + head * 32 + chunk * 8;
    async_ld16(qkv + gbase,       Qb + it * 512 + lane * 8);
    async_ld16(qkv + gbase + 512, Kb + it * 512 + lane * 8);
    vv[it] = *(const uint4*)(qkv + gbase + 1024);
  }
  __syncthreads();

  // ---- V^T build: Vt[d][j], j swizzled by ((d>>2)&3)<<4 ----
#pragma unroll
  for (int it = 0; it < 4; it++) {
    const int row = it * 16 + rrow;
    const u32* w = (const u32*)&vv[it];
#pragma unroll
    for (int tt = 0; tt < 8; tt++) {
      const int d = chunk * 8 + tt;
      const u16 val = (tt & 1) ? (u16)(w[tt >> 1] >> 16) : (u16)(w[tt >> 1] & 0xffffu);
      Vtb[d * 64 + (row ^ (((d >> 2) & 3) << 4))] = val;
    }
  }

  // ---- S^T = K * Q^T ----
  const int fswz = (l15 >> 1) & 3;
  bf16x8 kfrag[4], qfrag[4];
#pragma unroll
  for (int jm = 0; jm < 4; jm++)
    kfrag[jm] = *(const bf16x8*)(Kb + (jm * 16 + l15) * 32 + (quad ^ fswz) * 8);
#pragma unroll
  for (int in = 0; in < 4; in++)
    qfrag[in] = *(const bf16x8*)(Qb + (in * 16 + l15) * 32 + (quad ^ fswz) * 8);
  f32x4 sacc[4][4] = {};
#pragma unroll
  for (int jm = 0; jm < 4; jm++)
#pragma unroll
    for (int in = 0; in < 4; in++)
      sacc[jm][in] = __builtin_amdgcn_mfma_f32_16x16x32_bf16(kfrag[jm], qfrag[in], sacc[jm][in], 0, 0, 0);

  // ---- epilogue: scale + bias/mask gather, softmax over j ----
  const float* bT = biasT + (long)(cls * 16 + head) * 4096;
  const float sc = 0.17677669529663687f;
#pragma unroll
  for (int jm = 0; jm < 4; jm++) {
    const float* bp = bT + (jm * 16 + quad * 4) * 64 + l15;
#pragma unroll
    for (int in = 0; in < 4; in++)
#pragma unroll
      for (int r = 0; r < 4; r++)
        sacc[jm][in][r] = sacc[jm][in][r] * sc + bp[r * 64 + in * 16];
  }
  float linv[4];
#pragma unroll
  for (int in = 0; in < 4; in++) {
    float m = -1e30f;
#pragma unroll
    for (int jm = 0; jm < 4; jm++)
#pragma unroll
      for (int r = 0; r < 4; r++) m = fmaxf(m, sacc[jm][in][r]);
    m = fmaxf(m, __shfl_xor(m, 16));
    m = fmaxf(m, __shfl_xor(m, 32));
    float s = 0.f;
#pragma unroll
    for (int jm = 0; jm < 4; jm++)
#pragma unroll
      for (int r = 0; r < 4; r++) {
        const float e = __expf(sacc[jm][in][r] - m);
        sacc[jm][in][r] = e; s += e;
      }
    s += __shfl_xor(s, 16);
    s += __shfl_xor(s, 32);
    linv[in] = __builtin_amdgcn_rcpf(s);
  }

  // ---- P -> LDS bf16 (trunc), XOR-swizzled ----
#pragma unroll
  for (int in = 0; in < 4; in++) {
    const int i = in * 16 + l15;
    const int rot = (l15 & 3) << 4;
#pragma unroll
    for (int jm = 0; jm < 4; jm++) {
      const u32 lo = packtrunc2(sacc[jm][in][0], sacc[jm][in][1]);
      const u32 hi = packtrunc2(sacc[jm][in][2], sacc[jm][in][3]);
      uint2 u; u.x = lo; u.y = hi;
      *(uint2*)(Pb + i * 64 + ((jm * 16 + quad * 4) ^ rot)) = u;
    }
  }

  // ---- O^T = V^T * P ----
  f32x4 oacc[2][4] = {};
#pragma unroll
  for (int ks = 0; ks < 2; ks++) {
    bf16x8 vtf[2], pf[4];
#pragma unroll
    for (int dm = 0; dm < 2; dm++)
      vtf[dm] = *(const bf16x8*)(Vtb + (dm * 16 + l15) * 64 + ((ks * 32 + quad * 8) ^ ((l15 >> 2) << 4)));
#pragma unroll
    for (int in = 0; in < 4; in++)
      pf[in] = *(const bf16x8*)(Pb + (in * 16 + l15) * 64 + ((ks * 32 + quad * 8) ^ ((l15 & 3) << 4)));
#pragma unroll
    for (int dm = 0; dm < 2; dm++)
#pragma unroll
      for (int in = 0; in < 4; in++)
        oacc[dm][in] = __builtin_amdgcn_mfma_f32_16x16x32_bf16(vtf[dm], pf[in], oacc[dm][in], 0, 0, 0);
  }

  // ---- store O (4 consecutive channels per lane, 8B packed) ----
#pragma unroll
  for (int in = 0; in < 4; in++) {
    const int i = in * 16 + l15;
    if (i < 49) {
      const float inv = linv[in];
      const long base = (long)(win * 49 + i) * 512 + head * 32 + quad * 4;
#pragma unroll
      for (int dm = 0; dm < 2; dm++) {
        const float v0 = oacc[dm][in][0] * inv, v1 = oacc[dm][in][1] * inv;
        const float v2 = oacc[dm][in][2] * inv, v3 = oacc[dm][in][3] * inv;
        uint2 u; u.x = packtrunc2(v0, v1); u.y = packtrunc2(v2, v3);
        *(uint2*)(out + base + dm * 16) = u;
      }
    }
  }
}

// ---------------- x1 = x(CHW) + proj_out(pixel,C) ----------------
__global__ __launch_bounds__(256) void resid_kernel(const float* __restrict__ x,
    const float* __restrict__ proj, float* __restrict__ x1) {
  __shared__ float tile[32][65];
  const int p0 = blockIdx.x * 64;
  const int c0 = blockIdx.y * 32;
  const int t = threadIdx.x;
  {
    const int pl = t & 63;
    const int cl0 = t >> 6;
#pragma unroll
    for (int r = 0; r < 8; r++) {
      const int cl = r * 4 + cl0;
      tile[cl][pl] = x[(long)(c0 + cl) * NPIX + p0 + pl];
    }
  }
  __syncthreads();
  const int cl = t & 31;
  const int g = t >> 5;
#pragma unroll
  for (int pass = 0; pass < 8; pass++) {
    const int pl = pass * 8 + g;
    const long idx = (long)(p0 + pl) * 512 + c0 + cl;
    x1[idx] = tile[cl][pl] + proj[idx];
  }
}

// ---------------- LN2: wave per pixel row ----------------
__global__ __launch_bounds__(256) void ln2_apply(const float* __restrict__ x1,
    const float* __restrict__ gw, const float* __restrict__ gb, u16* __restrict__ x2) {
  const int wave = threadIdx.x >> 6;
  const int lane = threadIdx.x & 63;
  const int p = blockIdx.x * 4 + wave;
  const float4* row = (const float4*)(x1 + (long)p * 512);
  const float4 a = row[lane * 2];
  const float4 b = row[lane * 2 + 1];
  float s = a.x + a.y + a.z + a.w + b.x + b.y + b.z + b.w;
  float ss = a.x * a.x + a.y * a.y + a.z * a.z + a.w * a.w
           + b.x * b.x + b.y * b.y + b.z * b.z + b.w * b.w;
#pragma unroll
  for (int o = 32; o > 0; o >>= 1) { s += __shfl_xor(s, o); ss += __shfl_xor(ss, o); }
  const float m = s * (1.f / 512.f);
  const float var = ss * (1.f / 512.f) - m * m;
  const float rs = rsqrtf(var + 1e-5f);
  const float4 w0 = ((const float4*)gw)[lane * 2];
  const float4 w1 = ((const float4*)gw)[lane * 2 + 1];
  const float4 b0 = ((const float4*)gb)[lane * 2];
  const float4 b1 = ((const float4*)gb)[lane * 2 + 1];
  uint4 u;
  u.x = pack2((a.x - m) * rs * w0.x + b0.x, (a.y - m) * rs * w0.y + b0.y);
  u.y = pack2((a.z - m) * rs * w0.z + b0.z, (a.w - m) * rs * w0.w + b0.w);
  u.z = pack2((b.x - m) * rs * w1.x + b1.x, (b.y - m) * rs * w1.y + b1.y);
  u.w = pack2((b.z - m) * rs * w1.z + b1.z, (b.w - m) * rs * w1.w + b1.w);
  ((uint4*)(x2 + (long)p * 512))[lane] = u;
}

extern "C" void kernel_launch(void* const* d_in, const int* in_sizes, int n_in,
                              void* d_out, int out_size, void* d_ws, size_t ws_size,
                              hipStream_t stream) {
  (void)in_sizes; (void)n_in; (void)out_size; (void)ws_size;
  const float* x      = (const float*)d_in[0];
  const float* n1w    = (const float*)d_in[1];
  const float* n1b    = (const float*)d_in[2];
  const float* qkv_w  = (const float*)d_in[3];
  const float* qkv_b  = (const float*)d_in[4];
  const float* proj_w = (const float*)d_in[5];
  const float* proj_b = (const float*)d_in[6];
  const float* rpb    = (const float*)d_in[7];
  const float* n2w    = (const float*)d_in[8];
  const float* n2b    = (const float*)d_in[9];
  const float* fc1_w  = (const float*)d_in[10];
  const float* fc1_b  = (const float*)d_in[11];
  const float* fc2_w  = (const float*)d_in[12];
  const float* fc2_b  = (const float*)d_in[13];
  float* y = (float*)d_out;

  char* base = (char*)d_ws;
  size_t off = 0;
  auto alloc = [&](size_t b) { char* p = base + off; off += (b + 255) & ~(size_t)255; return p; };
  float* mean1 = (float*)alloc((size_t)NPIX * 4);
  float* rstd1 = (float*)alloc((size_t)NPIX * 4);
  float* psum  = (float*)alloc((size_t)16 * NPIX * 4);
  float* pssq  = (float*)alloc((size_t)16 * NPIX * 4);
  u16* Wq = (u16*)alloc((size_t)QKVN * CDIM * 2);
  u16* Wp = (u16*)alloc((size_t)CDIM * CDIM * 2);
  u16* W1 = (u16*)alloc((size_t)HIDDEN * CDIM * 2);
  u16* W2 = (u16*)alloc((size_t)CDIM * HIDDEN * 2);
  float* biasT = (float*)alloc((size_t)4 * 16 * 4096 * 4);
  u16* bufA = (u16*)alloc((size_t)NPIX * CDIM * 2);
  char* bufB = alloc((size_t)NPIX * QKVN * 2);
  float* x1 = (float*)alloc((size_t)NPIX * CDIM * 4);
  u16* hbuf = (u16*)alloc((size_t)NPIX * HIDDEN * 2);

  u16* xw      = bufA;
  u16* qkvbuf  = (u16*)bufB;
  u16* attnout = bufA;
  float* projout = (float*)bufB;
  u16* x2 = bufA;

  convert_weights<<<3072, 256, 0, stream>>>(qkv_w, proj_w, fc1_w, fc2_w, Wq, Wp, W1, W2);
  build_biasT<<<64, 256, 0, stream>>>(rpb, biasT);

  ln1_partial<<<dim3(49, 16), 256, 0, stream>>>(x, psum, pssq);
  ln1_stats<<<49, 256, 0, stream>>>(psum, pssq, mean1, rstd1);
  ln1_shift_part<<<dim3(196, 16), 256, 0, stream>>>(x, mean1, rstd1, n1w, n1b, xw);

  gemm_bt<true, false, false, false><<<dim3(98, QKVN / 128), 256, 0, stream>>>(xw, Wq, qkv_b, qkvbuf, nullptr, QKVN, CDIM);
  attn_mfma<<<1024, 256, 0, stream>>>(qkvbuf, biasT, attnout);
  gemm_bt<false, false, true, false><<<dim3(98, CDIM / 128), 256, 0, stream>>>(attnout, Wp, proj_b, projout, nullptr, CDIM, CDIM);

  resid_kernel<<<dim3(196, 16), 256, 0, stream>>>(x, projout, x1);
  ln2_apply<<<NPIX / 4, 256, 0, stream>>>(x1, n2w, n2b, x2);

  gemm_bt<true, true, false, false><<<dim3(98, HIDDEN / 128), 256, 0, stream>>>(x2, W1, fc1_b, hbuf, nullptr, HIDDEN, CDIM);
  // fc2 + residual + transpose-to-CHW fused; writes y directly
  gemm_bt<false, false, false, true><<<dim3(98, CDIM / 128), 256, 0, stream>>>(hbuf, W2, fc2_b, y, x1, CDIM, HIDDEN);
}